// Round 1
// baseline (382.403 us; speedup 1.0000x reference)
//
#include <hip/hip_runtime.h>
#include <stdint.h>

// BinarizeConv2dSDP: out = conv3x3(sign(x), sign(M), pad=1) * Alpha[o]
// Implemented as bf16 MFMA implicit GEMM over a zero-padded NHWC sign buffer.
// R1: correctness-first structured base (single-buffered LDS, no global_load_lds yet).

typedef __attribute__((ext_vector_type(8))) __bf16 bf16x8;
typedef __attribute__((ext_vector_type(4))) float floatx4;

#define N_IMG 32
#define C_IN  256
#define H_IMG 56
#define W_IMG 56
#define O_OUT 256
#define HP 58
#define WP 58
#define APAD_ELEMS ((size_t)N_IMG * HP * WP * C_IN)   // 27,557,888 bf16 = 55.1 MB
#define WPK_ELEMS  ((size_t)9 * O_OUT * C_IN)         // 589,824 bf16 = 1.18 MB

#define BO 128   // o-tile per block
#define BP 64    // pixel-tile per block (56 valid + 8 masked)
#define BK 64    // channels per stage
#define LDK 72   // padded LDS k-stride (144 B = 16*9: 16B-aligned rows, 2-way bank alias = free)

__device__ __forceinline__ unsigned short sgn_bf16(float x) {
    // sign() with sign(0)=0; +/-1.0 and 0.0 are exact in bf16
    return x > 0.f ? (unsigned short)0x3F80u
                   : (x < 0.f ? (unsigned short)0xBF80u : (unsigned short)0u);
}

// ---------------------------------------------------------------------------
// Kernel 1: NCHW fp32 -> zero-padded NHWC bf16 sign buffer (interior only;
// borders pre-zeroed by hipMemsetAsync). LDS transpose so both global sides
// are coalesced.
// grid = N*H*(C/64) = 32*56*4 = 7168 blocks of 256
__global__ __launch_bounds__(256) void binarize_act(
    const float* __restrict__ x, unsigned short* __restrict__ apad)
{
    __shared__ float tile[64 * 57];   // 57 stride: odd -> conflict-free transpose read
    int bid = blockIdx.x;
    int ct = bid & 3;
    int nh = bid >> 2;
    int n = nh / H_IMG;
    int h = nh - n * H_IMG;
    int c0 = ct * 64;
    int tid = threadIdx.x;

    const float* xb = x + ((size_t)(n * C_IN + c0) * H_IMG + h) * W_IMG;
#pragma unroll
    for (int j = 0; j < 14; ++j) {            // 64 ch * 56 w = 3584 = 14*256
        int idx = tid + 256 * j;
        int ci = idx / 56;
        int w  = idx - ci * 56;
        tile[ci * 57 + w] = xb[(size_t)ci * (H_IMG * W_IMG) + w];
    }
    __syncthreads();
    // write apad[n][h+1][w+1][c0+ci], lanes contiguous in ci (128 B / wave)
    unsigned short* ob = apad + ((size_t)(n * HP + (h + 1)) * WP + 1) * C_IN + c0;
#pragma unroll
    for (int j = 0; j < 14; ++j) {
        int idx = tid + 256 * j;
        int ci = idx & 63;
        int w  = idx >> 6;                    // < 56
        ob[(size_t)w * C_IN + ci] = sgn_bf16(tile[ci * 57 + w]);
    }
}

// ---------------------------------------------------------------------------
// Kernel 2: M (O,C,3,3) fp32 -> wpk[t][o][c] bf16 sign, t = kh*3+kw.
// grid = 256 blocks of 256 (one thread per (o,c))
__global__ __launch_bounds__(256) void pack_w(
    const float* __restrict__ M, unsigned short* __restrict__ wpk)
{
    int gid = blockIdx.x * 256 + threadIdx.x;   // 65536
    int o = gid >> 8;
    int c = gid & 255;
    const float* mb = M + (size_t)(o * C_IN + c) * 9;
#pragma unroll
    for (int t = 0; t < 9; ++t)
        wpk[((size_t)t * O_OUT + o) * C_IN + c] = sgn_bf16(mb[t]);
}

// ---------------------------------------------------------------------------
// Kernel 3: implicit GEMM. Block = (n,h) row-tile x o-tile.
// A-operand = weights W[o][k] (m=o), B-operand = act patches P[k][w] (n=w).
// C/D layout (verified): col = lane&15 = w, row = (lane>>4)*4 + r = o-sub.
// grid = 32*56*2 = 3584 blocks of 256 (4 waves; wave covers 32 o x 64 w)
__global__ __launch_bounds__(256) void bconv_gemm(
    const unsigned short* __restrict__ apad,
    const unsigned short* __restrict__ wpk,
    const float* __restrict__ alpha,
    float* __restrict__ out)
{
    __shared__ __align__(16) unsigned short Wl[BO * LDK];  // 18.4 KB
    __shared__ __align__(16) unsigned short Al[BP * LDK];  //  9.2 KB

    int bid = blockIdx.x;
    int ot = bid & 1;               // consecutive blocks share the act tile (L2)
    int nh = bid >> 1;
    int n = nh / H_IMG;
    int h = nh - n * H_IMG;
    int o_base = ot * BO;

    int tid  = threadIdx.x;
    int wv   = tid >> 6;
    int lane = tid & 63;
    int l15  = lane & 15;
    int quad = lane >> 4;

    floatx4 acc[2][4];
#pragma unroll
    for (int mt = 0; mt < 2; ++mt)
#pragma unroll
        for (int nt = 0; nt < 4; ++nt)
            acc[mt][nt] = (floatx4){0.f, 0.f, 0.f, 0.f};

#pragma unroll
    for (int t = 0; t < 9; ++t) {
        int kh = t / 3, kw = t - kh * 3;
        const unsigned short* wsrc = wpk + (size_t)t * O_OUT * C_IN;
        // output (h,w) reads padded input row h+kh, padded col w+kw
        const unsigned short* asrc = apad + ((size_t)(n * HP) + h + kh) * WP * C_IN;
#pragma unroll
        for (int c0 = 0; c0 < C_IN; c0 += BK) {
            __syncthreads();
            // stage weights: 128 o x 64 c, 16B chunks
#pragma unroll
            for (int j = 0; j < 4; ++j) {
                int idx = tid + 256 * j;        // < 1024
                int o = idx >> 3, cc = idx & 7;
                *(uint4*)&Wl[o * LDK + cc * 8] =
                    *(const uint4*)&wsrc[(size_t)(o_base + o) * C_IN + c0 + cc * 8];
            }
            // stage activations: 64 px x 64 c (px>=56 clamped; results masked at store)
#pragma unroll
            for (int j = 0; j < 2; ++j) {
                int idx = tid + 256 * j;        // < 512
                int p = idx >> 3, cc = idx & 7;
                int weff = p < 56 ? p : 55;
                *(uint4*)&Al[p * LDK + cc * 8] =
                    *(const uint4*)&asrc[(size_t)(weff + kw) * C_IN + c0 + cc * 8];
            }
            __syncthreads();
#pragma unroll
            for (int ks = 0; ks < 2; ++ks) {
                bf16x8 af[2], bf[4];
#pragma unroll
                for (int mt = 0; mt < 2; ++mt)
                    af[mt] = *(const bf16x8*)&Wl[(wv * 32 + mt * 16 + l15) * LDK + quad * 8 + ks * 32];
#pragma unroll
                for (int nt = 0; nt < 4; ++nt)
                    bf[nt] = *(const bf16x8*)&Al[(nt * 16 + l15) * LDK + quad * 8 + ks * 32];
#pragma unroll
                for (int mt = 0; mt < 2; ++mt)
#pragma unroll
                    for (int nt = 0; nt < 4; ++nt)
                        acc[mt][nt] = __builtin_amdgcn_mfma_f32_16x16x32_bf16(
                            af[mt], bf[nt], acc[mt][nt], 0, 0, 0);
            }
        }
    }

    // epilogue: out[n][o][h][w] = acc * alpha[o]; 16 contiguous w per quad store
#pragma unroll
    for (int mt = 0; mt < 2; ++mt) {
        int o0 = o_base + wv * 32 + mt * 16 + quad * 4;
#pragma unroll
        for (int r = 0; r < 4; ++r) {
            int o = o0 + r;
            float a = alpha[o];
            float* ob = out + ((size_t)(n * O_OUT + o) * H_IMG + h) * W_IMG;
#pragma unroll
            for (int nt = 0; nt < 4; ++nt) {
                int w = nt * 16 + l15;
                if (w < W_IMG) ob[w] = acc[mt][nt][r] * a;
            }
        }
    }
}

// ---------------------------------------------------------------------------
extern "C" void kernel_launch(void* const* d_in, const int* in_sizes, int n_in,
                              void* d_out, int out_size, void* d_ws, size_t ws_size,
                              hipStream_t stream) {
    const float* x     = (const float*)d_in[0];
    const float* M     = (const float*)d_in[1];
    const float* alpha = (const float*)d_in[2];
    float* out = (float*)d_out;

    unsigned short* apad = (unsigned short*)d_ws;          // 55.1 MB
    unsigned short* wpk  = apad + APAD_ELEMS;              // +1.18 MB (16B-aligned)

    // zero padding borders (ws re-poisoned to 0xAA before every launch)
    hipMemsetAsync(apad, 0, APAD_ELEMS * sizeof(unsigned short), stream);
    binarize_act<<<dim3(N_IMG * H_IMG * 4), dim3(256), 0, stream>>>(x, apad);
    pack_w<<<dim3(256), dim3(256), 0, stream>>>(M, wpk);
    bconv_gemm<<<dim3(N_IMG * H_IMG * 2), dim3(256), 0, stream>>>(apad, wpk, alpha, out);
}

// Round 3
// 328.296 us; speedup vs baseline: 1.1648x; 1.1648x over previous
//
#include <hip/hip_runtime.h>
#include <stdint.h>

// BinarizeConv2dSDP: out = conv3x3(sign(x), sign(M), pad=1) * Alpha[o]
// R3: 32x32x16 bf16 MFMA implicit GEMM; global_load_lds w16 staging;
//     FIXED bank swizzle (slot += pos>>1 -> full 8-quad spread, conflict floor);
//     uniform-exec staging (overlap trick, no masked glds); clamped in-bounds
//     act staging; flattened 256-px tiles; fused border zeroing.

typedef __attribute__((ext_vector_type(8))) __bf16 bf16x8;
typedef __attribute__((ext_vector_type(16))) float floatx16;

#define N_IMG 32
#define C_IN  256
#define O_OUT 256
#define HP 58
#define WP 58
#define GPI 3136                                    // 56*56 px per image
#define APAD_POS ((size_t)N_IMG * HP * WP)          // 107648 padded positions
#define APAD_ELEMS (APAD_POS * C_IN)                // 55.1 MB of ushort
#define TPI 13                                      // ceil(3136/256)
#define BK 32
#define AL_POS 268
#define AL_GRAN (AL_POS * 4)                        // 1072 16B granules
#define WL_GRAN (3 * 128 * 4)                       // 1536 16B granules

__device__ __forceinline__ unsigned short sgn_bf16(float x) {
    return x > 0.f ? (unsigned short)0x3F80u
                   : (x < 0.f ? (unsigned short)0xBF80u : (unsigned short)0u);
}

__device__ __forceinline__ void glds16(const unsigned short* g, unsigned short* l) {
    __builtin_amdgcn_global_load_lds(
        (const __attribute__((address_space(1))) unsigned int*)g,
        (__attribute__((address_space(3))) unsigned int*)l, 16, 0, 0);
}

// ---------------------------------------------------------------------------
// Binarize x -> zero-padded NHWC bf16 sign buffer, borders included.
__global__ __launch_bounds__(256) void binarize_act(
    const float* __restrict__ x, unsigned short* __restrict__ apad)
{
    int bid = blockIdx.x;
    int ct = bid & 3;
    int nh = bid >> 2;
    int n = nh / HP;
    int hp = nh - n * HP;
    int c0 = ct << 6;
    int tid = threadIdx.x;

    unsigned short* rowp = apad + ((size_t)(n * HP + hp) * WP) * C_IN + c0;

    if (hp == 0 || hp == HP - 1) {
        uint4 z = {0u, 0u, 0u, 0u};
        for (int i = tid; i < WP * 8; i += 256)
            *(uint4*)&rowp[(i >> 3) * C_IN + (i & 7) * 8] = z;
        return;
    }
    int h = hp - 1;
    __shared__ float tile[64 * 57];
    const float* xb = x + ((size_t)(n * C_IN + c0) * 56 + h) * 56;
#pragma unroll
    for (int j = 0; j < 14; ++j) {
        int idx = tid + 256 * j;
        int ci = idx / 56;
        int w  = idx - ci * 56;
        tile[ci * 57 + w] = xb[(size_t)ci * GPI + w];
    }
    __syncthreads();
    unsigned short* ob = rowp + C_IN;                // padded col 1
#pragma unroll
    for (int j = 0; j < 14; ++j) {
        int idx = tid + 256 * j;
        int ci = idx & 63;
        int w  = idx >> 6;
        ob[(size_t)w * C_IN + ci] = sgn_bf16(tile[ci * 57 + w]);
    }
    if (tid < 64) {                                  // pad cols 0 and 57
        rowp[tid] = 0;
        rowp[(size_t)(WP - 1) * C_IN + tid] = 0;
    }
}

// ---------------------------------------------------------------------------
// M (O,C,3,3) fp32 -> wpk[t][o][c] bf16 sign, t = kh*3+kw
__global__ __launch_bounds__(256) void pack_w(
    const float* __restrict__ M, unsigned short* __restrict__ wpk)
{
    int gid = blockIdx.x * 256 + threadIdx.x;
    int o = gid >> 8;
    int c = gid & 255;
    const float* mb = M + (size_t)(o * C_IN + c) * 9;
#pragma unroll
    for (int t = 0; t < 9; ++t)
        wpk[((size_t)t * O_OUT + o) * C_IN + c] = sgn_bf16(mb[t]);
}

// ---------------------------------------------------------------------------
// Implicit GEMM, 32x32x16 bf16 MFMA.
// Block = 128 o x 256 flat px. 4 waves 2x2: wave = 64 o x 128 px (mt=2, nt=4).
// LDS swizzle: granule(row, kslot) = row*4 + ((kslot + (row>>1)) & 3)
//   -> 8 consecutive rows cover all 8 bank-quads (conflict floor).
// Staging inverse: dest granule g: row=g>>2, src_slot=((g&3)-(row>>1))&3.
// A-frag: m=lane&31, k=(lane>>5)*8+j.  B-frag: n=lane&31, same k split.
// C/D: col=lane&31, row=(r&3)+8*(r>>2)+4*(lane>>5)   [m74/m101]
__global__ __launch_bounds__(256, 2) void bconv_gemm(
    const unsigned short* __restrict__ apad,
    const unsigned short* __restrict__ wpk,
    const float* __restrict__ alpha,
    float* __restrict__ out)
{
    __shared__ __align__(16) unsigned short Al[AL_GRAN * 8];   // 17.2 KB
    __shared__ __align__(16) unsigned short Wl[WL_GRAN * 8];   // 24.6 KB

    const int tid = threadIdx.x;
    const int wv = tid >> 6, lane = tid & 63;
    const int l31 = lane & 31, hb = lane >> 5;

    const int bid = blockIdx.x;
    const int img = bid / 26;
    const int rem = bid - img * 26;
    const int tl = rem >> 1, ot = rem & 1;
    const int g0 = tl << 8;
    const int h0 = g0 / 56, w0 = g0 - h0 * 56;
    const int o_base = ot << 7;
    const int Q0 = (img * HP + h0) * WP + w0;

    // act staging tables: slices 0..3 linear, slice 4 overlaps (granules 816..1071;
    // 816..1023 double-written with identical data -- pure function of dest granule)
    int al_pos[5], al_sl[5];
#pragma unroll
    for (int it = 0; it < 5; ++it) {
        int s = (it < 4) ? (tid + (it << 8)) : (tid + 816);
        int pos = s >> 2, gI = s & 3;
        al_pos[it] = pos;
        al_sl[it]  = ((gI - (pos >> 1)) & 3) << 3;
    }
    int wl_off[6];
#pragma unroll
    for (int it = 0; it < 6; ++it) {
        int s = tid + (it << 8);
        int r = s >> 2, gI = s & 3;
        int kw = r >> 7, o = r & 127;
        int sl = (gI - (r >> 1)) & 3;
        wl_off[it] = ((kw << 8) + o) * 256 + (sl << 3);
    }

    const int o_half  = (wv >> 1) << 6;
    const int px_half = (wv & 1) << 7;

    int pos_tab[4], pxg[4];
#pragma unroll
    for (int nt = 0; nt < 4; ++nt) {
        int px = px_half + (nt << 5) + l31;
        pxg[nt] = g0 + px;
        int pxc = (pxg[nt] < GPI) ? px : (GPI - 1 - g0);
        pos_tab[nt] = pxc + 2 * ((w0 + pxc) / 56);
    }

    floatx16 acc[2][4] = {};

    for (int kh = 0; kh < 3; ++kh) {
        const int rowbase = Q0 + kh * WP;
        const int plim = (int)APAD_POS - 1 - rowbase;   // clamp staging in-bounds
        const unsigned short* asrc0 = apad + ((size_t)rowbase << 8);
        const unsigned short* wsrc0 = wpk + ((size_t)(kh * 3) << 16) + ((size_t)o_base << 8);
        for (int c0 = 0; c0 < C_IN; c0 += BK) {
            const unsigned short* asrc = asrc0 + c0;
            const unsigned short* wsrc = wsrc0 + c0;
            __syncthreads();
#pragma unroll
            for (int it = 0; it < 4; ++it) {
                int p = al_pos[it] < plim ? al_pos[it] : plim;
                glds16(asrc + (((size_t)p) << 8) + al_sl[it],
                       &Al[(size_t)((it << 8) + (wv << 6)) << 3]);
            }
            {
                int p = al_pos[4] < plim ? al_pos[4] : plim;
                glds16(asrc + (((size_t)p) << 8) + al_sl[4],
                       &Al[(size_t)(816 + (wv << 6)) << 3]);
            }
#pragma unroll
            for (int it = 0; it < 6; ++it)
                glds16(wsrc + wl_off[it],
                       &Wl[(size_t)((it << 8) + (wv << 6)) << 3]);
            __syncthreads();

#pragma unroll
            for (int kw = 0; kw < 3; ++kw) {
#pragma unroll
                for (int ks = 0; ks < 2; ++ks) {
                    const int kslot = (ks << 1) + hb;
                    bf16x8 af[2], bf[4];
#pragma unroll
                    for (int mt = 0; mt < 2; ++mt) {
                        int r = (kw << 7) + o_half + (mt << 5) + l31;
                        int g = (r << 2) + ((kslot + (r >> 1)) & 3);
                        af[mt] = *(const bf16x8*)&Wl[(size_t)g << 3];
                    }
#pragma unroll
                    for (int nt = 0; nt < 4; ++nt) {
                        int pos = pos_tab[nt] + kw;
                        int g = (pos << 2) + ((kslot + (pos >> 1)) & 3);
                        bf[nt] = *(const bf16x8*)&Al[(size_t)g << 3];
                    }
#pragma unroll
                    for (int mt = 0; mt < 2; ++mt)
#pragma unroll
                        for (int nt = 0; nt < 4; ++nt)
                            acc[mt][nt] = __builtin_amdgcn_mfma_f32_32x32x16_bf16(
                                af[mt], bf[nt], acc[mt][nt], 0, 0, 0);
                }
            }
        }
    }

    // epilogue: out[img][o][px] = acc * alpha[o]
#pragma unroll
    for (int mt = 0; mt < 2; ++mt) {
#pragma unroll
        for (int r = 0; r < 16; ++r) {
            int o_loc = o_half + (mt << 5) + (r & 3) + ((r >> 2) << 3) + (hb << 2);
            int o_g = o_base + o_loc;
            float a = alpha[o_g];
            float* ob = out + ((size_t)(img * O_OUT + o_g)) * GPI;
#pragma unroll
            for (int nt = 0; nt < 4; ++nt) {
                if (pxg[nt] < GPI) ob[pxg[nt]] = acc[mt][nt][r] * a;
            }
        }
    }
}

// ---------------------------------------------------------------------------
extern "C" void kernel_launch(void* const* d_in, const int* in_sizes, int n_in,
                              void* d_out, int out_size, void* d_ws, size_t ws_size,
                              hipStream_t stream) {
    const float* x     = (const float*)d_in[0];
    const float* M     = (const float*)d_in[1];
    const float* alpha = (const float*)d_in[2];
    float* out = (float*)d_out;

    unsigned short* apad = (unsigned short*)d_ws;
    unsigned short* wpk  = apad + APAD_ELEMS;

    binarize_act<<<dim3(N_IMG * HP * 4), dim3(256), 0, stream>>>(x, apad);
    pack_w<<<dim3(256), dim3(256), 0, stream>>>(M, wpk);
    bconv_gemm<<<dim3(N_IMG * TPI * 2), dim3(256), 0, stream>>>(apad, wpk, alpha, out);
}

// Round 4
// 308.452 us; speedup vs baseline: 1.2397x; 1.0643x over previous
//
#include <hip/hip_runtime.h>
#include <stdint.h>

// BinarizeConv2dSDP: out = conv3x3(sign(x), sign(M), pad=1) * Alpha[o]
// R4: fp8 e4m3 path (+/-1 exact): mfma_f32_32x32x16_fp8_fp8, BK=64 ch/stage
//     (12 stages, same LDS bytes, 2x FLOP per staged/LDS byte vs R3);
//     vectorized binarize (float4 loads -> packed fp8 dwordx4 stores).

typedef __attribute__((ext_vector_type(16))) float floatx16;

#define N_IMG 32
#define C_IN  256
#define O_OUT 256
#define HP 58
#define WP 58
#define GPI 3136                                    // 56*56 px per image
#define APAD_POS ((size_t)N_IMG * HP * WP)          // 107648 padded positions
#define APAD_BYTES (APAD_POS * C_IN)                // 27.6 MB fp8
#define TPI 13
#define AL_GRAN 1072                                // 268 pos x 4 granules(16B)
#define WL_GRAN 1536                                // 3 kw x 128 o x 4 granules

__device__ __forceinline__ unsigned int sgn8(float x) {
    // fp8 e4m3fn: +1.0 = 0x38, -1.0 = 0xB8, 0 = 0x00
    return x > 0.f ? 0x38u : (x < 0.f ? 0xB8u : 0u);
}

__device__ __forceinline__ void glds16(const unsigned char* g, unsigned char* l) {
    __builtin_amdgcn_global_load_lds(
        (const __attribute__((address_space(1))) unsigned int*)g,
        (__attribute__((address_space(3))) unsigned int*)l, 16, 0, 0);
}

// ---------------------------------------------------------------------------
// Binarize x (NCHW fp32) -> zero-padded NHWC fp8 sign buffer.
// Block = one (n, hp, c-chunk of 64). float4 loads, LDS u32 tile (4 packed fp8),
// transposed dwordx4 stores (16 c per store).
__global__ __launch_bounds__(256) void binarize_act(
    const float* __restrict__ x, unsigned char* __restrict__ apad)
{
    int bid = blockIdx.x;
    int ct = bid & 3;
    int nh = bid >> 2;
    int n = nh / HP;
    int hp = nh - n * HP;
    int c0 = ct << 6;
    int tid = threadIdx.x;

    unsigned char* rowp = apad + ((size_t)(n * HP + hp) * WP) * C_IN + c0;
    uint4 z = {0u, 0u, 0u, 0u};

    if (hp == 0 || hp == HP - 1) {
        if (tid < 232) {                              // 58 cols x 4 granules
            int w = tid >> 2, gI = tid & 3;
            *(uint4*)(rowp + (size_t)w * C_IN + gI * 16) = z;
        }
        return;
    }
    int h = hp - 1;
    __shared__ unsigned int tile[64 * 15];            // 64 ch x 14 u32 (+1 pad)
    const float* xb = x + ((size_t)(n * C_IN + c0) * 56 + h) * 56;
#pragma unroll
    for (int j = 0; j < 4; ++j) {
        int idx = tid + 256 * j;                      // < 896 = 64*14
        if (idx < 896) {
            int ci = idx / 14;
            int w4 = idx - ci * 14;
            float4 v = *(const float4*)(xb + (size_t)ci * GPI + w4 * 4);
            tile[ci * 15 + w4] = sgn8(v.x) | (sgn8(v.y) << 8) |
                                 (sgn8(v.z) << 16) | (sgn8(v.w) << 24);
        }
    }
    __syncthreads();
    if (tid < 224) {                                  // 56 w x 4 c16-chunks
        int w = tid >> 2, c16 = tid & 3;
        int word = w >> 2, sh = (w & 3) * 8;
        int ci0 = c16 << 4;
        unsigned int res[4];
#pragma unroll
        for (int q = 0; q < 4; ++q) {
            unsigned int r = 0;
#pragma unroll
            for (int i = 0; i < 4; ++i) {
                unsigned int t = tile[(ci0 + q * 4 + i) * 15 + word];
                r |= ((t >> sh) & 0xFFu) << (8 * i);
            }
            res[q] = r;
        }
        *(uint4*)(rowp + (size_t)(w + 1) * C_IN + c16 * 16) =
            make_uint4(res[0], res[1], res[2], res[3]);
    } else if (tid < 232) {                           // zero pad cols 0 and 57
        int k = tid - 224;
        int col = (k < 4) ? 0 : (WP - 1);
        *(uint4*)(rowp + (size_t)col * C_IN + (k & 3) * 16) = z;
    }
}

// ---------------------------------------------------------------------------
// M (O,C,3,3) fp32 -> wpk[t][o][c] fp8 sign, t = kh*3+kw. Thread = (o, c4).
__global__ __launch_bounds__(256) void pack_w(
    const float* __restrict__ M, unsigned char* __restrict__ wpk)
{
    int gid = blockIdx.x * 256 + threadIdx.x;         // 16384
    int o = gid >> 6;
    int c4 = (gid & 63) << 2;
    const float* mb = M + (size_t)(o * C_IN + c4) * 9;
#pragma unroll
    for (int t = 0; t < 9; ++t) {
        unsigned int r = sgn8(mb[t]) | (sgn8(mb[9 + t]) << 8) |
                         (sgn8(mb[18 + t]) << 16) | (sgn8(mb[27 + t]) << 24);
        *(unsigned int*)(wpk + (size_t)t * 65536 + o * C_IN + c4) = r;
    }
}

// ---------------------------------------------------------------------------
// Implicit GEMM, fp8 e4m3 32x32x16 MFMA. Block = 128 o x 256 flat px,
// 4 waves 2x2 (wave = 64 o x 128 px, mt=2 nt=4). BK=64 ch/stage ->
// kh(3) x c0(4) = 12 stages. LDS row = 64 B/pos = 4 granules, swizzled
// granule(row,ks) = row*4 + ((ks + (row>>1)) & 3)  -> conflict-floor reads.
// A-frag: m=lane&31, k=(lane>>5)*8+j (8 fp8 = long). B-frag: n=lane&31.
// C/D: col=lane&31, row=(r&3)+8*(r>>2)+4*(lane>>5)  [shape-determined]
__global__ __launch_bounds__(256, 2) void bconv_gemm(
    const unsigned char* __restrict__ apad,
    const unsigned char* __restrict__ wpk,
    const float* __restrict__ alpha,
    float* __restrict__ out)
{
    __shared__ __align__(16) unsigned char Al[AL_GRAN * 16];   // 17.2 KB
    __shared__ __align__(16) unsigned char Wl[WL_GRAN * 16];   // 24.6 KB

    const int tid = threadIdx.x;
    const int wv = tid >> 6, lane = tid & 63;
    const int l31 = lane & 31, hb = lane >> 5;

    const int bid = blockIdx.x;
    const int img = bid / 26;
    const int rem = bid - img * 26;
    const int tl = rem >> 1, ot = rem & 1;
    const int g0 = tl << 8;
    const int h0 = g0 / 56, w0 = g0 - h0 * 56;
    const int o_base = ot << 7;
    const int Q0 = (img * HP + h0) * WP + w0;

    // act staging: slices 0..3 linear, slice 4 overlaps granules 816..1071
    int al_pos[5], al_sl[5];
#pragma unroll
    for (int it = 0; it < 5; ++it) {
        int s = (it < 4) ? (tid + (it << 8)) : (tid + 816);
        int pos = s >> 2, gI = s & 3;
        al_pos[it] = pos;
        al_sl[it]  = ((gI - (pos >> 1)) & 3) << 4;    // src byte slot
    }
    int wl_off[6];
#pragma unroll
    for (int it = 0; it < 6; ++it) {
        int s = tid + (it << 8);
        int r = s >> 2, gI = s & 3;
        int kw = r >> 7, o = r & 127;
        int sl = (gI - (r >> 1)) & 3;
        wl_off[it] = kw * 65536 + o * 256 + (sl << 4);
    }

    const int o_half  = (wv >> 1) << 6;
    const int px_half = (wv & 1) << 7;

    int pos_tab[4], pxg[4];
#pragma unroll
    for (int nt = 0; nt < 4; ++nt) {
        int px = px_half + (nt << 5) + l31;
        pxg[nt] = g0 + px;
        int pxc = (pxg[nt] < GPI) ? px : (GPI - 1 - g0);
        pos_tab[nt] = pxc + 2 * ((w0 + pxc) / 56);
    }

    floatx16 acc[2][4] = {};

    for (int kh = 0; kh < 3; ++kh) {
        const int rowbase = Q0 + kh * WP;
        const int plim = (int)APAD_POS - 1 - rowbase;
        const unsigned char* asrc0 = apad + ((size_t)rowbase << 8);
        const unsigned char* wsrc0 = wpk + (size_t)(kh * 3) * 65536 + ((size_t)o_base << 8);
        for (int c0 = 0; c0 < C_IN; c0 += 64) {
            const unsigned char* asrc = asrc0 + c0;
            const unsigned char* wsrc = wsrc0 + c0;
            __syncthreads();
#pragma unroll
            for (int it = 0; it < 4; ++it) {
                int p = al_pos[it] < plim ? al_pos[it] : plim;
                glds16(asrc + ((size_t)p << 8) + al_sl[it],
                       &Al[(size_t)((it << 8) + (wv << 6)) << 4]);
            }
            {
                int p = al_pos[4] < plim ? al_pos[4] : plim;
                glds16(asrc + ((size_t)p << 8) + al_sl[4],
                       &Al[(size_t)(816 + (wv << 6)) << 4]);
            }
#pragma unroll
            for (int it = 0; it < 6; ++it)
                glds16(wsrc + wl_off[it],
                       &Wl[(size_t)((it << 8) + (wv << 6)) << 4]);
            __syncthreads();

#pragma unroll
            for (int kw = 0; kw < 3; ++kw) {
#pragma unroll
                for (int ks = 0; ks < 4; ++ks) {
                    long af[2]; long bf[4];
#pragma unroll
                    for (int mt = 0; mt < 2; ++mt) {
                        int r = (kw << 7) + o_half + (mt << 5) + l31;
                        int g = (r << 2) + ((ks + (r >> 1)) & 3);
                        af[mt] = *(const long*)&Wl[(size_t)(g << 4) + (hb << 3)];
                    }
#pragma unroll
                    for (int nt = 0; nt < 4; ++nt) {
                        int pos = pos_tab[nt] + kw;
                        int g = (pos << 2) + ((ks + (pos >> 1)) & 3);
                        bf[nt] = *(const long*)&Al[(size_t)(g << 4) + (hb << 3)];
                    }
#pragma unroll
                    for (int mt = 0; mt < 2; ++mt)
#pragma unroll
                        for (int nt = 0; nt < 4; ++nt)
                            acc[mt][nt] = __builtin_amdgcn_mfma_f32_32x32x16_fp8_fp8(
                                af[mt], bf[nt], acc[mt][nt], 0, 0, 0);
                }
            }
        }
    }

    // epilogue: out[img][o][px] = acc * alpha[o]
#pragma unroll
    for (int mt = 0; mt < 2; ++mt) {
#pragma unroll
        for (int r = 0; r < 16; ++r) {
            int o_loc = o_half + (mt << 5) + (r & 3) + ((r >> 2) << 3) + (hb << 2);
            int o_g = o_base + o_loc;
            float a = alpha[o_g];
            float* ob = out + ((size_t)(img * O_OUT + o_g)) * GPI;
#pragma unroll
            for (int nt = 0; nt < 4; ++nt) {
                if (pxg[nt] < GPI) ob[pxg[nt]] = acc[mt][nt][r] * a;
            }
        }
    }
}

// ---------------------------------------------------------------------------
extern "C" void kernel_launch(void* const* d_in, const int* in_sizes, int n_in,
                              void* d_out, int out_size, void* d_ws, size_t ws_size,
                              hipStream_t stream) {
    const float* x     = (const float*)d_in[0];
    const float* M     = (const float*)d_in[1];
    const float* alpha = (const float*)d_in[2];
    float* out = (float*)d_out;

    unsigned char* apad = (unsigned char*)d_ws;
    unsigned char* wpk  = apad + APAD_BYTES;

    binarize_act<<<dim3(N_IMG * HP * 4), dim3(256), 0, stream>>>(x, apad);
    pack_w<<<dim3(64), dim3(256), 0, stream>>>(M, wpk);
    bconv_gemm<<<dim3(N_IMG * TPI * 2), dim3(256), 0, stream>>>(apad, wpk, alpha, out);
}

// Round 5
// 299.711 us; speedup vs baseline: 1.2759x; 1.0292x over previous
//
#include <hip/hip_runtime.h>
#include <stdint.h>

// BinarizeConv2dSDP: out = conv3x3(sign(x), sign(M), pad=1) * Alpha[o]
// R5: binarize_act v2 — one block per (n,hp) row, all 256 ch; two-stage LDS
//     transpose with conflict-free bank mappings; 1 KB/wave contiguous stores.
//     GEMM unchanged from R4 (fp8 e4m3 32x32x16, verified absmax 0.0).

typedef __attribute__((ext_vector_type(16))) float floatx16;

#define N_IMG 32
#define C_IN  256
#define O_OUT 256
#define HP 58
#define WP 58
#define GPI 3136                                    // 56*56 px per image
#define APAD_POS ((size_t)N_IMG * HP * WP)          // 107648 padded positions
#define APAD_BYTES (APAD_POS * C_IN)                // 27.6 MB fp8
#define TPI 13
#define AL_GRAN 1072
#define WL_GRAN 1536

__device__ __forceinline__ unsigned int sgn8(float x) {
    // fp8 e4m3fn: +1.0 = 0x38, -1.0 = 0xB8, 0 = 0x00
    return x > 0.f ? 0x38u : (x < 0.f ? 0xB8u : 0u);
}

__device__ __forceinline__ void glds16(const unsigned char* g, unsigned char* l) {
    __builtin_amdgcn_global_load_lds(
        (const __attribute__((address_space(1))) unsigned int*)g,
        (__attribute__((address_space(3))) unsigned int*)l, 16, 0, 0);
}

// ---------------------------------------------------------------------------
// Binarize x (NCHW fp32) -> zero-padded NHWC fp8 sign buffer.
// Block = one (n, hp) padded row, ALL 256 channels.
// Phase 1: float4 loads -> tile[ci][word] (u32 = 4 w-packed sign bytes).
// Phase 2a: repack w-packed -> channel-packed u32 in LDS2[w][cq]
//   (reads: 4-lane same-addr broadcast x 16 addrs over 8 banks = 2-way, free).
// Phase 2b: uint4 reads from LDS2 -> 1 KB contiguous store per wave.
__global__ __launch_bounds__(256) void binarize_act(
    const float* __restrict__ x, unsigned char* __restrict__ apad)
{
    int bid = blockIdx.x;
    int n = bid / HP;
    int hp = bid - n * HP;
    int tid = threadIdx.x;

    unsigned char* rowp = apad + ((size_t)(n * HP + hp) * WP) * C_IN;
    uint4 z = {0u, 0u, 0u, 0u};

    if (hp == 0 || hp == HP - 1) {                    // border rows: zero 58x256B
#pragma unroll
        for (int j = 0; j < 4; ++j) {
            int t = tid + 256 * j;                    // < 928 = 58*16
            if (t < WP * 16) {
                int w = t >> 4, g = t & 15;
                *(uint4*)(rowp + (size_t)w * C_IN + g * 16) = z;
            }
        }
        return;
    }
    int h = hp - 1;

    __shared__ unsigned int tile[C_IN * 15];          // [ci][word0..13], stride 15
    __shared__ unsigned int lds2[56 * 65];            // [w][cq0..63], stride 65

    const float* xb = x + ((size_t)n * C_IN) * GPI + h * 56;
#pragma unroll
    for (int j = 0; j < 14; ++j) {                    // 256 ch x 14 float4
        int t = tid + 256 * j;
        int ci = t / 14;
        int w4 = t - ci * 14;
        float4 v = *(const float4*)(xb + (size_t)ci * GPI + w4 * 4);
        tile[ci * 15 + w4] = sgn8(v.x) | (sgn8(v.y) << 8) |
                             (sgn8(v.z) << 16) | (sgn8(v.w) << 24);
    }
    __syncthreads();

    // Phase 2a: t = whi*256 + cq*4 + wlo ; w = whi*4+wlo ; cq = channel quad
#pragma unroll
    for (int j = 0; j < 14; ++j) {
        int t = tid + 256 * j;                        // < 3584 = 14*64*4
        int wlo = t & 3;
        int cq  = (t >> 2) & 63;
        int whi = t >> 8;
        int sh = wlo * 8;
        unsigned int r = 0;
#pragma unroll
        for (int i = 0; i < 4; ++i) {
            unsigned int v = tile[(cq * 4 + i) * 15 + whi];
            r |= ((v >> sh) & 0xFFu) << (8 * i);
        }
        lds2[(whi * 4 + wlo) * 65 + cq] = r;
    }
    __syncthreads();

    // Phase 2b: 56 w x 16 uint4 -> contiguous stores (pos w+1, c = g*16..)
#pragma unroll
    for (int j = 0; j < 4; ++j) {
        int t = tid + 256 * j;                        // < 896 = 56*16
        if (t < 896) {
            int w = t >> 4, g = t & 15;
            uint4 v;
            v.x = lds2[w * 65 + g * 4 + 0];
            v.y = lds2[w * 65 + g * 4 + 1];
            v.z = lds2[w * 65 + g * 4 + 2];
            v.w = lds2[w * 65 + g * 4 + 3];
            *(uint4*)(rowp + (size_t)(w + 1) * C_IN + g * 16) = v;
        }
    }
    if (tid < 32) {                                   // zero pad cols 0 and 57
        int g = tid & 15;
        int col = (tid >> 4) * (WP - 1);
        *(uint4*)(rowp + (size_t)col * C_IN + g * 16) = z;
    }
}

// ---------------------------------------------------------------------------
// M (O,C,3,3) fp32 -> wpk[t][o][c] fp8 sign, t = kh*3+kw. Thread = (o, c4).
__global__ __launch_bounds__(256) void pack_w(
    const float* __restrict__ M, unsigned char* __restrict__ wpk)
{
    int gid = blockIdx.x * 256 + threadIdx.x;         // 16384
    int o = gid >> 6;
    int c4 = (gid & 63) << 2;
    const float* mb = M + (size_t)(o * C_IN + c4) * 9;
#pragma unroll
    for (int t = 0; t < 9; ++t) {
        unsigned int r = sgn8(mb[t]) | (sgn8(mb[9 + t]) << 8) |
                         (sgn8(mb[18 + t]) << 16) | (sgn8(mb[27 + t]) << 24);
        *(unsigned int*)(wpk + (size_t)t * 65536 + o * C_IN + c4) = r;
    }
}

// ---------------------------------------------------------------------------
// Implicit GEMM, fp8 e4m3 32x32x16 MFMA (unchanged from R4; absmax 0.0).
__global__ __launch_bounds__(256, 2) void bconv_gemm(
    const unsigned char* __restrict__ apad,
    const unsigned char* __restrict__ wpk,
    const float* __restrict__ alpha,
    float* __restrict__ out)
{
    __shared__ __align__(16) unsigned char Al[AL_GRAN * 16];   // 17.2 KB
    __shared__ __align__(16) unsigned char Wl[WL_GRAN * 16];   // 24.6 KB

    const int tid = threadIdx.x;
    const int wv = tid >> 6, lane = tid & 63;
    const int l31 = lane & 31, hb = lane >> 5;

    const int bid = blockIdx.x;
    const int img = bid / 26;
    const int rem = bid - img * 26;
    const int tl = rem >> 1, ot = rem & 1;
    const int g0 = tl << 8;
    const int h0 = g0 / 56, w0 = g0 - h0 * 56;
    const int o_base = ot << 7;
    const int Q0 = (img * HP + h0) * WP + w0;

    int al_pos[5], al_sl[5];
#pragma unroll
    for (int it = 0; it < 5; ++it) {
        int s = (it < 4) ? (tid + (it << 8)) : (tid + 816);
        int pos = s >> 2, gI = s & 3;
        al_pos[it] = pos;
        al_sl[it]  = ((gI - (pos >> 1)) & 3) << 4;
    }
    int wl_off[6];
#pragma unroll
    for (int it = 0; it < 6; ++it) {
        int s = tid + (it << 8);
        int r = s >> 2, gI = s & 3;
        int kw = r >> 7, o = r & 127;
        int sl = (gI - (r >> 1)) & 3;
        wl_off[it] = kw * 65536 + o * 256 + (sl << 4);
    }

    const int o_half  = (wv >> 1) << 6;
    const int px_half = (wv & 1) << 7;

    int pos_tab[4], pxg[4];
#pragma unroll
    for (int nt = 0; nt < 4; ++nt) {
        int px = px_half + (nt << 5) + l31;
        pxg[nt] = g0 + px;
        int pxc = (pxg[nt] < GPI) ? px : (GPI - 1 - g0);
        pos_tab[nt] = pxc + 2 * ((w0 + pxc) / 56);
    }

    floatx16 acc[2][4] = {};

    for (int kh = 0; kh < 3; ++kh) {
        const int rowbase = Q0 + kh * WP;
        const int plim = (int)APAD_POS - 1 - rowbase;
        const unsigned char* asrc0 = apad + ((size_t)rowbase << 8);
        const unsigned char* wsrc0 = wpk + (size_t)(kh * 3) * 65536 + ((size_t)o_base << 8);
        for (int c0 = 0; c0 < C_IN; c0 += 64) {
            const unsigned char* asrc = asrc0 + c0;
            const unsigned char* wsrc = wsrc0 + c0;
            __syncthreads();
#pragma unroll
            for (int it = 0; it < 4; ++it) {
                int p = al_pos[it] < plim ? al_pos[it] : plim;
                glds16(asrc + ((size_t)p << 8) + al_sl[it],
                       &Al[(size_t)((it << 8) + (wv << 6)) << 4]);
            }
            {
                int p = al_pos[4] < plim ? al_pos[4] : plim;
                glds16(asrc + ((size_t)p << 8) + al_sl[4],
                       &Al[(size_t)(816 + (wv << 6)) << 4]);
            }
#pragma unroll
            for (int it = 0; it < 6; ++it)
                glds16(wsrc + wl_off[it],
                       &Wl[(size_t)((it << 8) + (wv << 6)) << 4]);
            __syncthreads();

#pragma unroll
            for (int kw = 0; kw < 3; ++kw) {
#pragma unroll
                for (int ks = 0; ks < 4; ++ks) {
                    long af[2]; long bf[4];
#pragma unroll
                    for (int mt = 0; mt < 2; ++mt) {
                        int r = (kw << 7) + o_half + (mt << 5) + l31;
                        int g = (r << 2) + ((ks + (r >> 1)) & 3);
                        af[mt] = *(const long*)&Wl[(size_t)(g << 4) + (hb << 3)];
                    }
#pragma unroll
                    for (int nt = 0; nt < 4; ++nt) {
                        int pos = pos_tab[nt] + kw;
                        int g = (pos << 2) + ((ks + (pos >> 1)) & 3);
                        bf[nt] = *(const long*)&Al[(size_t)(g << 4) + (hb << 3)];
                    }
#pragma unroll
                    for (int mt = 0; mt < 2; ++mt)
#pragma unroll
                        for (int nt = 0; nt < 4; ++nt)
                            acc[mt][nt] = __builtin_amdgcn_mfma_f32_32x32x16_fp8_fp8(
                                af[mt], bf[nt], acc[mt][nt], 0, 0, 0);
                }
            }
        }
    }

#pragma unroll
    for (int mt = 0; mt < 2; ++mt) {
#pragma unroll
        for (int r = 0; r < 16; ++r) {
            int o_loc = o_half + (mt << 5) + (r & 3) + ((r >> 2) << 3) + (hb << 2);
            int o_g = o_base + o_loc;
            float a = alpha[o_g];
            float* ob = out + ((size_t)(img * O_OUT + o_g)) * GPI;
#pragma unroll
            for (int nt = 0; nt < 4; ++nt) {
                if (pxg[nt] < GPI) ob[pxg[nt]] = acc[mt][nt][r] * a;
            }
        }
    }
}

// ---------------------------------------------------------------------------
extern "C" void kernel_launch(void* const* d_in, const int* in_sizes, int n_in,
                              void* d_out, int out_size, void* d_ws, size_t ws_size,
                              hipStream_t stream) {
    const float* x     = (const float*)d_in[0];
    const float* M     = (const float*)d_in[1];
    const float* alpha = (const float*)d_in[2];
    float* out = (float*)d_out;

    unsigned char* apad = (unsigned char*)d_ws;
    unsigned char* wpk  = apad + APAD_BYTES;

    binarize_act<<<dim3(N_IMG * HP), dim3(256), 0, stream>>>(x, apad);
    pack_w<<<dim3(64), dim3(256), 0, stream>>>(M, wpk);
    bconv_gemm<<<dim3(N_IMG * TPI * 2), dim3(256), 0, stream>>>(apad, wpk, alpha, out);
}